// Round 2
// baseline (132.552 us; speedup 1.0000x reference)
//
#include <hip/hip_runtime.h>

// Sizes (fixed by the problem)
#define NB 16
#define NQ 128
#define NK 512
#define NH 128
#define NDV 128

#define TQ 4      // q rows per block (== waves per block)
#define KC 64     // k rows staged per LDS chunk
#define KPAD 132  // 128 + 4 floats: b128 reads land 2-way conflicts (free)

typedef __attribute__((ext_vector_type(8))) short short8;
typedef __attribute__((ext_vector_type(4))) float f32x4;
typedef __attribute__((ext_vector_type(2))) float f32x2;

#define C2LOG2E 2.8853900817779268f  // 2*log2(e): folded into projections
#define LOG2E   1.4426950408889634f

__device__ __forceinline__ short f2bf(float x) {   // RNE f32 -> bf16
    unsigned u = __float_as_uint(x);
    unsigned r = (u + 0x7fffu + ((u >> 16) & 1u)) >> 16;
    return (short)r;
}
__device__ __forceinline__ float bf2f(short s) {
    return __uint_as_float(((unsigned)(unsigned short)s) << 16);
}

// ---------------------------------------------------------------------------
// Projection: Y[rows,128] = X[rows,128] @ W[128,128] * 2log2e, fp32 in/out.
// Split-bf16 MFMA: x = hi+lo, Y ~= Ah*Bh + Al*Bh + Ah*Bl (rel err ~2^-16).
// One block = 16 rows x 128 h (8 waves, one 16x16 MFMA tile each).
// Blocks [0,128) -> queries (2048 rows), [128,640) -> keys (8192 rows).
// ---------------------------------------------------------------------------
__global__ __launch_bounds__(512) void proj_kernel(
    const float* __restrict__ Xq, const float* __restrict__ Wq,
    const float* __restrict__ Xk, const float* __restrict__ Wk,
    float* __restrict__ qp, float* __restrict__ kp)
{
    int blk = blockIdx.x;
    const float* X; const float* W; float* Y; int row0;
    if (blk < 128) { X = Xq; W = Wq; Y = qp; row0 = blk * 16; }
    else           { X = Xk; W = Wk; Y = kp; row0 = (blk - 128) * 16; }

    int wave = threadIdx.x >> 6;   // 0..7 -> 16-wide h tile
    int lane = threadIdx.x & 63;
    int m    = lane & 15;          // row (A) / col (B,D) within tile
    int quad = lane >> 4;          // 0..3
    int h0   = wave * 16;

    f32x4 acc = {0.f, 0.f, 0.f, 0.f};
#pragma unroll
    for (int ks = 0; ks < 4; ++ks) {
        int kb = ks * 32 + quad * 8;
        short8 ah, al, bh, bl;
        const float* xp = X + (size_t)(row0 + m) * NH + kb;
#pragma unroll
        for (int j = 0; j < 8; ++j) {
            float x = xp[j];                         // contiguous 32B/lane
            short hx = f2bf(x);
            ah[j] = hx; al[j] = f2bf(x - bf2f(hx));
            float w = W[(size_t)(kb + j) * NH + h0 + m];  // W is L1/L2-resident
            short hw = f2bf(w);
            bh[j] = hw; bl[j] = f2bf(w - bf2f(hw));
        }
        acc = __builtin_amdgcn_mfma_f32_16x16x32_bf16(ah, bl, acc, 0, 0, 0);
        acc = __builtin_amdgcn_mfma_f32_16x16x32_bf16(al, bh, acc, 0, 0, 0);
        acc = __builtin_amdgcn_mfma_f32_16x16x32_bf16(ah, bh, acc, 0, 0, 0);
    }
    // D: col = lane&15, row = quad*4 + reg  [verified layout]
#pragma unroll
    for (int r = 0; r < 4; ++r)
        Y[(size_t)(row0 + quad * 4 + r) * NH + h0 + m] = acc[r] * C2LOG2E;
}

// ---------------------------------------------------------------------------
// Attention: one block = (b, tile of TQ q's). wave=q, lane=k within chunk.
// score = Wsum - sum_h 2*wv[h] / (exp2(qp'+kp') + 1)   (== sum_h wv*tanh)
// Only k < valid_len computed (reference's -1e6 mask underflows to exactly 0).
// ---------------------------------------------------------------------------
__global__ __launch_bounds__(256) void attn_kernel(
    const float* __restrict__ qp, const float* __restrict__ kp,
    const float* __restrict__ V, const int* __restrict__ vlen,
    const float* __restrict__ wv, float* __restrict__ out)
{
    __shared__ float s_kp[KC * KPAD];   // 33792 B
    __shared__ float s_qp[TQ * NH];     //  2048 B
    __shared__ float s_wv[NH];          //   512 B  (holds 2*wv)
    __shared__ float s_sc[TQ * NK];     //  8192 B
    __shared__ float s_rinv[TQ];

    int b  = blockIdx.x >> 5;          // 32 q-tiles per batch
    int q0 = (blockIdx.x & 31) * TQ;
    int t  = threadIdx.x;
    int wave = t >> 6, lane = t & 63;

    for (int i = t; i < TQ * NH; i += 256)
        s_qp[i] = qp[(size_t)(b * NQ + q0) * NH + i];
    if (t < NH) s_wv[t] = 2.0f * wv[t];
    __syncthreads();

    int nv = vlen[b];
    nv = max(1, min(NK, nv));

    // Wsum = sum_h wv[h]  (s_wv holds 2*wv -> *0.5)
    float sum2 = s_wv[lane] + s_wv[lane + 64];
#pragma unroll
    for (int off = 32; off; off >>= 1) sum2 += __shfl_xor(sum2, off);
    float wsum = 0.5f * sum2;

    int nchunk = (nv + KC - 1) / KC;
    for (int c = 0; c < nchunk; ++c) {
        int k0 = c * KC;
        __syncthreads();
        // stage kp chunk: 64 rows x 128 f32, coalesced f32x4
        for (int i = t; i < KC * 32; i += 256) {
            int row = i >> 5, c4 = i & 31;
            *(f32x4*)&s_kp[row * KPAD + c4 * 4] =
                *(const f32x4*)&kp[((size_t)(b * NK + k0 + row)) * NH + c4 * 4];
        }
        __syncthreads();

        const float* kq = &s_kp[lane * KPAD];
        const float* qr = &s_qp[wave * NH];
        float a0 = 0.f, a1 = 0.f, a2 = 0.f, a3 = 0.f;  // 4 chains: hide latency
#pragma unroll 8
        for (int h = 0; h < NH; h += 4) {
            f32x4 k4 = *(const f32x4*)(kq + h);
            f32x4 q4 = *(const f32x4*)(qr + h);   // broadcast (free)
            f32x4 w4 = *(const f32x4*)(s_wv + h); // broadcast (free)
            float t0 = q4[0] + k4[0];
            float t1 = q4[1] + k4[1];
            float t2 = q4[2] + k4[2];
            float t3 = q4[3] + k4[3];
            float e0 = __builtin_amdgcn_exp2f(t0);
            float e1 = __builtin_amdgcn_exp2f(t1);
            float e2 = __builtin_amdgcn_exp2f(t2);
            float e3 = __builtin_amdgcn_exp2f(t3);
            a0 = fmaf(w4[0], __builtin_amdgcn_rcpf(e0 + 1.0f), a0);
            a1 = fmaf(w4[1], __builtin_amdgcn_rcpf(e1 + 1.0f), a1);
            a2 = fmaf(w4[2], __builtin_amdgcn_rcpf(e2 + 1.0f), a2);
            a3 = fmaf(w4[3], __builtin_amdgcn_rcpf(e3 + 1.0f), a3);
        }
        float sc = wsum - ((a0 + a1) + (a2 + a3));
        int kg = k0 + lane;
        s_sc[wave * NK + kg] = (kg < nv) ? sc : -1e30f;
    }
    __syncthreads();

    // softmax over k (wave owns q = q0+wave)
    float mx = -1e30f;
    for (int k = lane; k < nv; k += 64) mx = fmaxf(mx, s_sc[wave * NK + k]);
#pragma unroll
    for (int off = 32; off; off >>= 1) mx = fmaxf(mx, __shfl_xor(mx, off));
    float l = 0.f;
    for (int k = lane; k < nv; k += 64) {
        float p = __builtin_amdgcn_exp2f((s_sc[wave * NK + k] - mx) * LOG2E);
        s_sc[wave * NK + k] = p;
        l += p;
    }
#pragma unroll
    for (int off = 32; off; off >>= 1) l += __shfl_xor(l, off);
    if (lane == 0) s_rinv[wave] = 1.0f / l;
    __syncthreads();

    // AV: wave owns q, lane owns a dv pair; V loads coalesced 8B/lane
    int dv0 = lane * 2;
    const float* pv = &s_sc[wave * NK];
    const float* Vb = V + (size_t)b * NK * NDV + dv0;
    float o0 = 0.f, o1 = 0.f;
    int k = 0;
    for (; k + 4 <= nv; k += 4) {
        f32x4 p4 = *(const f32x4*)(pv + k);       // one ds_read_b128 / 4 k
#pragma unroll
        for (int j = 0; j < 4; ++j) {
            f32x2 v = *(const f32x2*)(Vb + (size_t)(k + j) * NDV);
            o0 = fmaf(p4[j], v[0], o0);
            o1 = fmaf(p4[j], v[1], o1);
        }
    }
    for (; k < nv; ++k) {
        float p = pv[k];
        f32x2 v = *(const f32x2*)(Vb + (size_t)k * NDV);
        o0 = fmaf(p, v[0], o0);
        o1 = fmaf(p, v[1], o1);
    }
    float rinv = s_rinv[wave];
    size_t ob = ((size_t)b * NQ + q0 + wave) * NDV + dv0;
    f32x2 o = {o0 * rinv, o1 * rinv};
    *(f32x2*)&out[ob] = o;
}

extern "C" void kernel_launch(void* const* d_in, const int* in_sizes, int n_in,
                              void* d_out, int out_size, void* d_ws, size_t ws_size,
                              hipStream_t stream) {
    const float* q  = (const float*)d_in[0];  // (16,128,128) f32
    const float* ks = (const float*)d_in[1];  // (16,512,128) f32
    const float* vs = (const float*)d_in[2];  // (16,512,128) f32
    const int*   vl = (const int*)d_in[3];    // (16,) i32
    const float* wq = (const float*)d_in[4];  // (128,128) f32
    const float* wk = (const float*)d_in[5];  // (128,128) f32
    const float* wv = (const float*)d_in[6];  // (128,) f32

    float* qp = (float*)d_ws;            // 2048*128 f32 = 1 MB (prescaled)
    float* kp = qp + 2048 * 128;         // 8192*128 f32 = 4 MB (prescaled)

    proj_kernel<<<640, 512, 0, stream>>>(q, wq, ks, wk, qp, kp);
    attn_kernel<<<NB * (NQ / TQ), 256, 0, stream>>>(qp, kp, vs, vl, wv,
                                                    (float*)d_out);
}

// Round 3
// 132.445 us; speedup vs baseline: 1.0008x; 1.0008x over previous
//
#include <hip/hip_runtime.h>

// Sizes (fixed by the problem)
#define NB 16
#define NQ 128
#define NK 512
#define NH 128
#define NDV 128

#define TQ 4      // q rows per attn block (== waves per block)
#define KC 64     // k rows staged per LDS chunk
#define KPAD 132  // 128+4 floats: measured 0 bank conflicts with this stride
#define PR 64     // rows per proj block
#define WTP 136   // wt row stride in shorts (16B-aligned rows)

typedef __attribute__((ext_vector_type(8))) short short8;
typedef __attribute__((ext_vector_type(4))) float f32x4;
typedef __attribute__((ext_vector_type(2))) float f32x2;

#define C2LOG2E 2.8853900817779268f  // 2*log2(e): folded into proj epilogue
#define LOG2E   1.4426950408889634f

__device__ __forceinline__ short f2bf(float x) {   // RNE f32 -> bf16
    unsigned u = __float_as_uint(x);
    unsigned r = (u + 0x7fffu + ((u >> 16) & 1u)) >> 16;
    return (short)r;
}
__device__ __forceinline__ float bf2f(short s) {
    return __uint_as_float(((unsigned)(unsigned short)s) << 16);
}

// ---------------------------------------------------------------------------
// Projection + exp: E = exp2(2log2e * X@W), fp32 in/out via split-bf16 MFMA.
// W staged once per block in LDS, transposed + split hi/lo (b128-friendly
// B-fragments). Block = 64 rows x 128 h: 4 waves, each 16 rows x 8 h-tiles.
// Blocks [0,32) -> Eq (2048 rows), [32,160) -> Ek (8192 rows).
// tanh(x) = 1 - 2/(exp2(2log2e*(q+k))+1) = 1 - 2/(Eq*Ek+1).
// ---------------------------------------------------------------------------
__global__ __launch_bounds__(256) void proj_kernel(
    const float* __restrict__ Xq, const float* __restrict__ Wq,
    const float* __restrict__ Xk, const float* __restrict__ Wk,
    const float* __restrict__ wv,
    float* __restrict__ Eq, float* __restrict__ Ek, float* __restrict__ w2)
{
    __shared__ short wt_hi[128 * WTP];   // 34816 B
    __shared__ short wt_lo[128 * WTP];   // 34816 B

    int blk = blockIdx.x;
    int t   = threadIdx.x;
    if (blk == 0 && t < NH) w2[t] = 2.0f * wv[t];

    const float* X; const float* W; float* Y; int row0;
    if (blk < 32) { X = Xq; W = Wq; Y = Eq; row0 = blk * PR; }
    else          { X = Xk; W = Wk; Y = Ek; row0 = (blk - 32) * PR; }

    // Stage W transposed + split: wt[h][k]. Reads fully coalesced f32x4.
    for (int i = t; i < 128 * 32; i += 256) {
        int k = i >> 5, h4 = (i & 31) << 2;
        f32x4 w4 = *(const f32x4*)&W[(size_t)k * NH + h4];
#pragma unroll
        for (int j = 0; j < 4; ++j) {
            short hi = f2bf(w4[j]);
            wt_hi[(h4 + j) * WTP + k] = hi;
            wt_lo[(h4 + j) * WTP + k] = f2bf(w4[j] - bf2f(hi));
        }
    }
    __syncthreads();

    int wave = t >> 6, lane = t & 63;
    int m = lane & 15, quad = lane >> 4;

    // A-fragments for this wave's 16 rows, all K=128 (kept in regs, reused
    // across 8 h-tiles). Row = m, k = ks*32 + quad*8 + j.
    short8 AH[4], AL[4];
    const float* xr = X + (size_t)(row0 + wave * 16 + m) * NH + quad * 8;
#pragma unroll
    for (int ks = 0; ks < 4; ++ks) {
#pragma unroll
        for (int j = 0; j < 8; ++j) {
            float x = xr[ks * 32 + j];
            short hi = f2bf(x);
            AH[ks][j] = hi;
            AL[ks][j] = f2bf(x - bf2f(hi));
        }
    }

#pragma unroll
    for (int ht = 0; ht < 8; ++ht) {
        int h0 = ht * 16;
        f32x4 acc = {0.f, 0.f, 0.f, 0.f};
#pragma unroll
        for (int ks = 0; ks < 4; ++ks) {
            int bo = (h0 + m) * WTP + ks * 32 + quad * 8;  // B[k][n]: n=m
            short8 bh = *(const short8*)&wt_hi[bo];
            short8 bl = *(const short8*)&wt_lo[bo];
            acc = __builtin_amdgcn_mfma_f32_16x16x32_bf16(AH[ks], bl, acc, 0, 0, 0);
            acc = __builtin_amdgcn_mfma_f32_16x16x32_bf16(AL[ks], bh, acc, 0, 0, 0);
            acc = __builtin_amdgcn_mfma_f32_16x16x32_bf16(AH[ks], bh, acc, 0, 0, 0);
        }
        // D: col = lane&15, row = quad*4 + r  [verified layout]
#pragma unroll
        for (int r = 0; r < 4; ++r)
            Y[(size_t)(row0 + wave * 16 + quad * 4 + r) * NH + h0 + m] =
                __builtin_amdgcn_exp2f(acc[r] * C2LOG2E);
    }
}

// ---------------------------------------------------------------------------
// Attention: block = (b, 4 q's). wave=q, lane=k. Per element:
//   score += w2[h] * rcp(Eq[q][h]*Ek[k][h] + 1);  final = Wsum - score.
// Eq row + w2 are wave-uniform (scalar loads); Ek staged in LDS.
// Only k < valid_len computed (masked softmax underflows to exact 0).
// ---------------------------------------------------------------------------
__global__ __launch_bounds__(256) void attn_kernel(
    const float* __restrict__ Eq, const float* __restrict__ Ek,
    const float* __restrict__ V, const int* __restrict__ vlen,
    const float* __restrict__ w2, float* __restrict__ out)
{
    __shared__ float s_ek[KC * KPAD];   // 33792 B
    __shared__ float s_sc[TQ * NK];     //  8192 B
    __shared__ float s_rinv[TQ];

    int b  = blockIdx.x >> 5;          // 32 q-tiles per batch
    int q0 = (blockIdx.x & 31) * TQ;
    int t  = threadIdx.x;
    int lane = t & 63;
    int wave = __builtin_amdgcn_readfirstlane(t >> 6);  // uniform -> s_loads

    int nv = vlen[b];
    nv = max(1, min(NK, nv));

    // Wsum = sum_h wv[h] = 0.5 * sum_h w2[h]
    float s2 = w2[lane] + w2[lane + 64];
#pragma unroll
    for (int off = 32; off; off >>= 1) s2 += __shfl_xor(s2, off);
    float wsum = 0.5f * s2;

    const float* eqr = Eq + ((size_t)b * NQ + q0 + wave) * NH;  // uniform

    int nchunk = (nv + KC - 1) / KC;
    for (int c = 0; c < nchunk; ++c) {
        int k0 = c * KC;
        __syncthreads();
        for (int i = t; i < KC * 32; i += 256) {
            int row = i >> 5, c4 = i & 31;
            *(f32x4*)&s_ek[row * KPAD + c4 * 4] =
                *(const f32x4*)&Ek[((size_t)b * NK + k0 + row) * NH + c4 * 4];
        }
        __syncthreads();

        const float* ekl = &s_ek[lane * KPAD];
        float a0 = 0.f, a1 = 0.f, a2 = 0.f, a3 = 0.f;
        float a4 = 0.f, a5 = 0.f, a6 = 0.f, a7 = 0.f;  // 8 rcp chains
#pragma unroll
        for (int h = 0; h < NH; h += 8) {
            f32x4 kA = *(const f32x4*)(ekl + h);
            f32x4 kB = *(const f32x4*)(ekl + h + 4);
            a0 = fmaf(w2[h+0], __builtin_amdgcn_rcpf(fmaf(eqr[h+0], kA[0], 1.0f)), a0);
            a1 = fmaf(w2[h+1], __builtin_amdgcn_rcpf(fmaf(eqr[h+1], kA[1], 1.0f)), a1);
            a2 = fmaf(w2[h+2], __builtin_amdgcn_rcpf(fmaf(eqr[h+2], kA[2], 1.0f)), a2);
            a3 = fmaf(w2[h+3], __builtin_amdgcn_rcpf(fmaf(eqr[h+3], kA[3], 1.0f)), a3);
            a4 = fmaf(w2[h+4], __builtin_amdgcn_rcpf(fmaf(eqr[h+4], kB[0], 1.0f)), a4);
            a5 = fmaf(w2[h+5], __builtin_amdgcn_rcpf(fmaf(eqr[h+5], kB[1], 1.0f)), a5);
            a6 = fmaf(w2[h+6], __builtin_amdgcn_rcpf(fmaf(eqr[h+6], kB[2], 1.0f)), a6);
            a7 = fmaf(w2[h+7], __builtin_amdgcn_rcpf(fmaf(eqr[h+7], kB[3], 1.0f)), a7);
        }
        float sc = wsum - (((a0 + a1) + (a2 + a3)) + ((a4 + a5) + (a6 + a7)));
        int kg = k0 + lane;
        s_sc[wave * NK + kg] = (kg < nv) ? sc : -1e30f;
    }
    __syncthreads();

    // softmax over k (wave owns q = q0+wave)
    float mx = -1e30f;
    for (int k = lane; k < nv; k += 64) mx = fmaxf(mx, s_sc[wave * NK + k]);
#pragma unroll
    for (int off = 32; off; off >>= 1) mx = fmaxf(mx, __shfl_xor(mx, off));
    float l = 0.f;
    for (int k = lane; k < nv; k += 64) {
        float p = __builtin_amdgcn_exp2f((s_sc[wave * NK + k] - mx) * LOG2E);
        s_sc[wave * NK + k] = p;
        l += p;
    }
#pragma unroll
    for (int off = 32; off; off >>= 1) l += __shfl_xor(l, off);
    if (lane == 0) s_rinv[wave] = 1.0f / l;
    __syncthreads();

    // AV: wave owns q, lane owns a dv pair; V loads coalesced 8B/lane
    int dv0 = lane * 2;
    const float* pv = &s_sc[wave * NK];
    const float* Vb = V + (size_t)b * NK * NDV + dv0;
    float o0 = 0.f, o1 = 0.f;
    int k = 0;
    for (; k + 4 <= nv; k += 4) {
        f32x4 p4 = *(const f32x4*)(pv + k);       // one ds_read_b128 / 4 k
#pragma unroll
        for (int j = 0; j < 4; ++j) {
            f32x2 v = *(const f32x2*)(Vb + (size_t)(k + j) * NDV);
            o0 = fmaf(p4[j], v[0], o0);
            o1 = fmaf(p4[j], v[1], o1);
        }
    }
    for (; k < nv; ++k) {
        float p = pv[k];
        f32x2 v = *(const f32x2*)(Vb + (size_t)k * NDV);
        o0 = fmaf(p, v[0], o0);
        o1 = fmaf(p, v[1], o1);
    }
    float rinv = s_rinv[wave];
    size_t ob = ((size_t)b * NQ + q0 + wave) * NDV + dv0;
    f32x2 o = {o0 * rinv, o1 * rinv};
    *(f32x2*)&out[ob] = o;
}

extern "C" void kernel_launch(void* const* d_in, const int* in_sizes, int n_in,
                              void* d_out, int out_size, void* d_ws, size_t ws_size,
                              hipStream_t stream) {
    const float* q  = (const float*)d_in[0];  // (16,128,128) f32
    const float* ks = (const float*)d_in[1];  // (16,512,128) f32
    const float* vs = (const float*)d_in[2];  // (16,512,128) f32
    const int*   vl = (const int*)d_in[3];    // (16,) i32
    const float* wq = (const float*)d_in[4];  // (128,128) f32
    const float* wk = (const float*)d_in[5];  // (128,128) f32
    const float* wv = (const float*)d_in[6];  // (128,) f32

    float* Eq = (float*)d_ws;                 // 2048*128 f32 = 1 MB
    float* Ek = Eq + 2048 * 128;              // 8192*128 f32 = 4 MB
    float* w2 = Ek + (size_t)8192 * 128;      // 128 f32

    proj_kernel<<<160, 256, 0, stream>>>(q, wq, ks, wk, wv, Eq, Ek, w2);
    attn_kernel<<<NB * (NQ / TQ), 256, 0, stream>>>(Eq, Ek, vs, vl, w2,
                                                    (float*)d_out);
}

// Round 4
// 125.547 us; speedup vs baseline: 1.0558x; 1.0549x over previous
//
#include <hip/hip_runtime.h>

// Sizes (fixed by the problem)
#define NB 16
#define NQ 128
#define NK 512
#define NH 128
#define NDV 128

#define TQ 4      // q rows per attn block (== waves per block)
#define KC 64     // k rows staged per LDS chunk
#define KPAD 132  // 128+4 floats: measured 0 bank conflicts with this stride
#define PR 64     // rows per proj block
#define WTP 136   // wt row stride in shorts (16B-aligned rows)

typedef __attribute__((ext_vector_type(8))) short short8;
typedef __attribute__((ext_vector_type(4))) float f32x4;
typedef __attribute__((ext_vector_type(2))) float f32x2;

#define C2LOG2E 2.8853900817779268f  // 2*log2(e): folded into proj epilogue
#define LOG2E   1.4426950408889634f

__device__ __forceinline__ short f2bf(float x) {   // RNE f32 -> bf16
    unsigned u = __float_as_uint(x);
    unsigned r = (u + 0x7fffu + ((u >> 16) & 1u)) >> 16;
    return (short)r;
}
__device__ __forceinline__ float bf2f(short s) {
    return __uint_as_float(((unsigned)(unsigned short)s) << 16);
}

// ---------------------------------------------------------------------------
// Projection + exp: E = exp2(2log2e * X@W), fp32 in/out via split-bf16 MFMA.
// (unchanged from round 3 — will re-examine via counters once attn is fast)
// ---------------------------------------------------------------------------
__global__ __launch_bounds__(256) void proj_kernel(
    const float* __restrict__ Xq, const float* __restrict__ Wq,
    const float* __restrict__ Xk, const float* __restrict__ Wk,
    const float* __restrict__ wv,
    float* __restrict__ Eq, float* __restrict__ Ek, float* __restrict__ w2)
{
    __shared__ short wt_hi[128 * WTP];   // 34816 B
    __shared__ short wt_lo[128 * WTP];   // 34816 B

    int blk = blockIdx.x;
    int t   = threadIdx.x;
    if (blk == 0 && t < NH) w2[t] = 2.0f * wv[t];

    const float* X; const float* W; float* Y; int row0;
    if (blk < 32) { X = Xq; W = Wq; Y = Eq; row0 = blk * PR; }
    else          { X = Xk; W = Wk; Y = Ek; row0 = (blk - 32) * PR; }

    for (int i = t; i < 128 * 32; i += 256) {
        int k = i >> 5, h4 = (i & 31) << 2;
        f32x4 w4 = *(const f32x4*)&W[(size_t)k * NH + h4];
#pragma unroll
        for (int j = 0; j < 4; ++j) {
            short hi = f2bf(w4[j]);
            wt_hi[(h4 + j) * WTP + k] = hi;
            wt_lo[(h4 + j) * WTP + k] = f2bf(w4[j] - bf2f(hi));
        }
    }
    __syncthreads();

    int wave = t >> 6, lane = t & 63;
    int m = lane & 15, quad = lane >> 4;

    short8 AH[4], AL[4];
    const float* xr = X + (size_t)(row0 + wave * 16 + m) * NH + quad * 8;
#pragma unroll
    for (int ks = 0; ks < 4; ++ks) {
#pragma unroll
        for (int j = 0; j < 8; ++j) {
            float x = xr[ks * 32 + j];
            short hi = f2bf(x);
            AH[ks][j] = hi;
            AL[ks][j] = f2bf(x - bf2f(hi));
        }
    }

#pragma unroll
    for (int ht = 0; ht < 8; ++ht) {
        int h0 = ht * 16;
        f32x4 acc = {0.f, 0.f, 0.f, 0.f};
#pragma unroll
        for (int ks = 0; ks < 4; ++ks) {
            int bo = (h0 + m) * WTP + ks * 32 + quad * 8;
            short8 bh = *(const short8*)&wt_hi[bo];
            short8 bl = *(const short8*)&wt_lo[bo];
            acc = __builtin_amdgcn_mfma_f32_16x16x32_bf16(AH[ks], bl, acc, 0, 0, 0);
            acc = __builtin_amdgcn_mfma_f32_16x16x32_bf16(AL[ks], bh, acc, 0, 0, 0);
            acc = __builtin_amdgcn_mfma_f32_16x16x32_bf16(AH[ks], bh, acc, 0, 0, 0);
        }
#pragma unroll
        for (int r = 0; r < 4; ++r)
            Y[(size_t)(row0 + wave * 16 + quad * 4 + r) * NH + h0 + m] =
                __builtin_amdgcn_exp2f(acc[r] * C2LOG2E);
    }
}

// ---------------------------------------------------------------------------
// Attention: block = (b, 4 q's). wave=q, lane=k. Per element:
//   score += w2[h] * rcp(Eq[q][h]*Ek[k][h] + 1);  final = Wsum - score.
// All inner-loop operands come from LDS (no SMEM in loop): per-wave
// (eq,w2)-pair rows broadcast-read, Ek lane-read. Only k < valid_len done.
// ---------------------------------------------------------------------------
__global__ __launch_bounds__(256) void attn_kernel(
    const float* __restrict__ Eq, const float* __restrict__ Ek,
    const float* __restrict__ V, const int* __restrict__ vlen,
    const float* __restrict__ w2, float* __restrict__ out)
{
    __shared__ float s_ek[KC * KPAD];    // 33792 B
    __shared__ float s_qw[TQ * NH * 2];  //  4096 B (eq,w2 interleaved per wave)
    __shared__ float s_sc[TQ * NK];      //  8192 B
    __shared__ float s_rinv[TQ];

    int b  = blockIdx.x & 15;            // interleave batches: tail balance
    int q0 = (blockIdx.x >> 4) * TQ;
    int t  = threadIdx.x;
    int lane = t & 63, wave = t >> 6;

    // Fill (eq, w2) pair rows: one pair per thread x2. Coalesced reads.
    for (int i = t; i < TQ * NH; i += 256) {
        int q = i >> 7, h = i & 127;
        s_qw[i * 2]     = Eq[((size_t)b * NQ + q0 + q) * NH + h];
        s_qw[i * 2 + 1] = w2[h];
    }

    int nv = vlen[b];
    nv = max(1, min(NK, nv));

    // Wsum = sum_h wv[h] = 0.5 * sum_h w2[h]
    float s2 = w2[lane] + w2[lane + 64];
#pragma unroll
    for (int off = 32; off; off >>= 1) s2 += __shfl_xor(s2, off);
    float wsum = 0.5f * s2;

    int nchunk = (nv + KC - 1) / KC;
    for (int c = 0; c < nchunk; ++c) {
        int k0 = c * KC;
        __syncthreads();
        for (int i = t; i < KC * 32; i += 256) {
            int row = i >> 5, c4 = i & 31;
            *(f32x4*)&s_ek[row * KPAD + c4 * 4] =
                *(const f32x4*)&Ek[((size_t)b * NK + k0 + row) * NH + c4 * 4];
        }
        __syncthreads();

        const float* ekl = &s_ek[lane * KPAD];
        const float* qw  = &s_qw[wave * NH * 2];
        float a0 = 0.f, a1 = 0.f, a2 = 0.f, a3 = 0.f;
        float a4 = 0.f, a5 = 0.f, a6 = 0.f, a7 = 0.f;
#pragma unroll
        for (int hh = 0; hh < NH; hh += 8) {
            f32x4 kA = *(const f32x4*)(ekl + hh);
            f32x4 kB = *(const f32x4*)(ekl + hh + 4);
            f32x4 p0 = *(const f32x4*)(qw + hh * 2);      // eq,w2,eq,w2
            f32x4 p1 = *(const f32x4*)(qw + hh * 2 + 4);
            f32x4 p2 = *(const f32x4*)(qw + hh * 2 + 8);
            f32x4 p3 = *(const f32x4*)(qw + hh * 2 + 12);
            a0 = fmaf(p0[1], __builtin_amdgcn_rcpf(fmaf(p0[0], kA[0], 1.0f)), a0);
            a1 = fmaf(p0[3], __builtin_amdgcn_rcpf(fmaf(p0[2], kA[1], 1.0f)), a1);
            a2 = fmaf(p1[1], __builtin_amdgcn_rcpf(fmaf(p1[0], kA[2], 1.0f)), a2);
            a3 = fmaf(p1[3], __builtin_amdgcn_rcpf(fmaf(p1[2], kA[3], 1.0f)), a3);
            a4 = fmaf(p2[1], __builtin_amdgcn_rcpf(fmaf(p2[0], kB[0], 1.0f)), a4);
            a5 = fmaf(p2[3], __builtin_amdgcn_rcpf(fmaf(p2[2], kB[1], 1.0f)), a5);
            a6 = fmaf(p3[1], __builtin_amdgcn_rcpf(fmaf(p3[0], kB[2], 1.0f)), a6);
            a7 = fmaf(p3[3], __builtin_amdgcn_rcpf(fmaf(p3[2], kB[3], 1.0f)), a7);
        }
        float sc = wsum - (((a0 + a1) + (a2 + a3)) + ((a4 + a5) + (a6 + a7)));
        int kg = k0 + lane;
        s_sc[wave * NK + kg] = (kg < nv) ? sc : -1e30f;
    }
    __syncthreads();

    // softmax over k (wave owns q = q0+wave)
    float mx = -1e30f;
    for (int k = lane; k < nv; k += 64) mx = fmaxf(mx, s_sc[wave * NK + k]);
#pragma unroll
    for (int off = 32; off; off >>= 1) mx = fmaxf(mx, __shfl_xor(mx, off));
    float l = 0.f;
    for (int k = lane; k < nv; k += 64) {
        float p = __builtin_amdgcn_exp2f((s_sc[wave * NK + k] - mx) * LOG2E);
        s_sc[wave * NK + k] = p;
        l += p;
    }
#pragma unroll
    for (int off = 32; off; off >>= 1) l += __shfl_xor(l, off);
    if (lane == 0) s_rinv[wave] = 1.0f / l;
    __syncthreads();

    // AV: wave owns q, lane owns a dv pair; 8 independent loads in flight.
    int dv0 = lane * 2;
    const float* pv = &s_sc[wave * NK];
    const float* Vb = V + (size_t)b * NK * NDV + dv0;
    float o0 = 0.f, o1 = 0.f;
    int k = 0;
    for (; k + 8 <= nv; k += 8) {
        f32x4 pA = *(const f32x4*)(pv + k);
        f32x4 pB = *(const f32x4*)(pv + k + 4);
        f32x2 v0 = *(const f32x2*)(Vb + (size_t)(k + 0) * NDV);
        f32x2 v1 = *(const f32x2*)(Vb + (size_t)(k + 1) * NDV);
        f32x2 v2 = *(const f32x2*)(Vb + (size_t)(k + 2) * NDV);
        f32x2 v3 = *(const f32x2*)(Vb + (size_t)(k + 3) * NDV);
        f32x2 v4 = *(const f32x2*)(Vb + (size_t)(k + 4) * NDV);
        f32x2 v5 = *(const f32x2*)(Vb + (size_t)(k + 5) * NDV);
        f32x2 v6 = *(const f32x2*)(Vb + (size_t)(k + 6) * NDV);
        f32x2 v7 = *(const f32x2*)(Vb + (size_t)(k + 7) * NDV);
        o0 = fmaf(pA[0], v0[0], o0); o1 = fmaf(pA[0], v0[1], o1);
        o0 = fmaf(pA[1], v1[0], o0); o1 = fmaf(pA[1], v1[1], o1);
        o0 = fmaf(pA[2], v2[0], o0); o1 = fmaf(pA[2], v2[1], o1);
        o0 = fmaf(pA[3], v3[0], o0); o1 = fmaf(pA[3], v3[1], o1);
        o0 = fmaf(pB[0], v4[0], o0); o1 = fmaf(pB[0], v4[1], o1);
        o0 = fmaf(pB[1], v5[0], o0); o1 = fmaf(pB[1], v5[1], o1);
        o0 = fmaf(pB[2], v6[0], o0); o1 = fmaf(pB[2], v6[1], o1);
        o0 = fmaf(pB[3], v7[0], o0); o1 = fmaf(pB[3], v7[1], o1);
    }
    for (; k < nv; ++k) {
        float p = pv[k];
        f32x2 v = *(const f32x2*)(Vb + (size_t)k * NDV);
        o0 = fmaf(p, v[0], o0);
        o1 = fmaf(p, v[1], o1);
    }
    float rinv = s_rinv[wave];
    size_t ob = ((size_t)b * NQ + q0 + wave) * NDV + dv0;
    f32x2 o = {o0 * rinv, o1 * rinv};
    *(f32x2*)&out[ob] = o;
}

extern "C" void kernel_launch(void* const* d_in, const int* in_sizes, int n_in,
                              void* d_out, int out_size, void* d_ws, size_t ws_size,
                              hipStream_t stream) {
    const float* q  = (const float*)d_in[0];  // (16,128,128) f32
    const float* ks = (const float*)d_in[1];  // (16,512,128) f32
    const float* vs = (const float*)d_in[2];  // (16,512,128) f32
    const int*   vl = (const int*)d_in[3];    // (16,) i32
    const float* wq = (const float*)d_in[4];  // (128,128) f32
    const float* wk = (const float*)d_in[5];  // (128,128) f32
    const float* wv = (const float*)d_in[6];  // (128,) f32

    float* Eq = (float*)d_ws;                 // 2048*128 f32 = 1 MB
    float* Ek = Eq + 2048 * 128;              // 8192*128 f32 = 4 MB
    float* w2 = Ek + (size_t)8192 * 128;      // 128 f32

    proj_kernel<<<160, 256, 0, stream>>>(q, wq, ks, wk, wv, Eq, Ek, w2);
    attn_kernel<<<NB * (NQ / TQ), 256, 0, stream>>>(Eq, Ek, vs, vl, w2,
                                                    (float*)d_out);
}